// Round 1
// baseline (145.777 us; speedup 1.0000x reference)
//
#include <hip/hip_runtime.h>

#define NNODES 100000
#define NEDGES 1600000
#define HID 16
#define MSG 16
#define NTYPE 16
#define NCLS 64

__device__ __forceinline__ float sigmoid_f(float x) {
    return 1.0f / (1.0f + __expf(-x));
}

__device__ __forceinline__ float tanh_f(float x) {
    x = fminf(fmaxf(x, -15.0f), 15.0f);
    float e = __expf(2.0f * x);
    return (e - 1.0f) / (e + 1.0f);
}

// ---------------------------------------------------------------------------
// Edge kernel: 16 lanes per edge; lane i computes msg[e][i] = sum_h A[t][i][h]*feat[src][h]
// A staged in LDS transposed: At[t*256 + h*16 + i] = edge_emb[t*256 + i*16 + h]
// so the 16 lanes of an edge read consecutive LDS addresses for each h.
// ---------------------------------------------------------------------------
__global__ __launch_bounds__(256) void ggnn_edge(
    const float* __restrict__ feat,
    const int* __restrict__ src,
    const int* __restrict__ dst,
    const int* __restrict__ etype,
    const float* __restrict__ edge_emb,
    float* __restrict__ magg)
{
    __shared__ float At[NTYPE * MSG * HID];
    for (int idx = threadIdx.x; idx < NTYPE * MSG * HID; idx += 256) {
        int t   = idx >> 8;
        int rem = idx & 255;
        int i   = rem >> 4;   // msg row
        int hh  = rem & 15;   // hid col
        At[(t << 8) | (hh << 4) | i] = edge_emb[idx];
    }
    __syncthreads();

    const long long total = (long long)NEDGES * MSG;
    for (long long w = (long long)blockIdx.x * 256 + threadIdx.x; w < total;
         w += (long long)gridDim.x * 256) {
        const int e = (int)(w >> 4);
        const int i = (int)(w & 15);
        const int s = src[e];
        const int d = dst[e];
        const int t = etype[e];

        const float4* fp = (const float4*)(feat + (size_t)s * HID);
        const float4 f0 = fp[0];
        const float4 f1 = fp[1];
        const float4 f2 = fp[2];
        const float4 f3 = fp[3];

        const float* a = At + (t << 8) + i;
        float acc;
        acc  = a[0*16]*f0.x + a[1*16]*f0.y + a[2*16]*f0.z + a[3*16]*f0.w;
        acc += a[4*16]*f1.x + a[5*16]*f1.y + a[6*16]*f1.z + a[7*16]*f1.w;
        acc += a[8*16]*f2.x + a[9*16]*f2.y + a[10*16]*f2.z + a[11*16]*f2.w;
        acc += a[12*16]*f3.x + a[13*16]*f3.y + a[14*16]*f3.z + a[15*16]*f3.w;

        atomicAdd(magg + (size_t)d * MSG + i, acc);
    }
}

// ---------------------------------------------------------------------------
// Node kernel: one thread per node. GRU (PyTorch gate order r,z,n) + output head.
// Weight accesses are wave-uniform -> compiler emits scalar loads (SGPR FMAs).
// ---------------------------------------------------------------------------
__global__ __launch_bounds__(256) void ggnn_node(
    const float* __restrict__ feat,
    const float* __restrict__ magg,
    const float* __restrict__ W_ih,
    const float* __restrict__ W_hh,
    const float* __restrict__ b_ih,
    const float* __restrict__ b_hh,
    const float* __restrict__ W_out,
    const float* __restrict__ b_out,
    float* __restrict__ out)
{
    const int n = blockIdx.x * 256 + threadIdx.x;
    if (n >= NNODES) return;

    float hv[HID], mv[MSG];
    {
        const float4* hp = (const float4*)(feat + (size_t)n * HID);
        const float4* mp = (const float4*)(magg + (size_t)n * MSG);
        #pragma unroll
        for (int q = 0; q < 4; q++) {
            float4 a = hp[q];
            hv[4*q+0] = a.x; hv[4*q+1] = a.y; hv[4*q+2] = a.z; hv[4*q+3] = a.w;
            float4 b = mp[q];
            mv[4*q+0] = b.x; mv[4*q+1] = b.y; mv[4*q+2] = b.z; mv[4*q+3] = b.w;
        }
    }

    float hnew[HID];
    #pragma unroll
    for (int i = 0; i < HID; i++) {
        float xr = b_ih[i], xz = b_ih[16 + i], xn = b_ih[32 + i];
        float hr = b_hh[i], hz = b_hh[16 + i], hn = b_hh[32 + i];
        #pragma unroll
        for (int j = 0; j < HID; j++) {
            xr += W_ih[(i)      * 16 + j] * mv[j];
            xz += W_ih[(16 + i) * 16 + j] * mv[j];
            xn += W_ih[(32 + i) * 16 + j] * mv[j];
            hr += W_hh[(i)      * 16 + j] * hv[j];
            hz += W_hh[(16 + i) * 16 + j] * hv[j];
            hn += W_hh[(32 + i) * 16 + j] * hv[j];
        }
        float r  = sigmoid_f(xr + hr);
        float z  = sigmoid_f(xz + hz);
        float nn = tanh_f(xn + r * hn);
        hnew[i] = (1.0f - z) * nn + z * hv[i];
    }

    float4* op = (float4*)(out + (size_t)n * NCLS);
    #pragma unroll
    for (int c4 = 0; c4 < NCLS / 4; c4++) {
        float a0 = b_out[4*c4+0], a1 = b_out[4*c4+1], a2 = b_out[4*c4+2], a3 = b_out[4*c4+3];
        #pragma unroll
        for (int j = 0; j < HID; j++) {
            a0 += W_out[(4*c4+0) * 16 + j] * hnew[j];
            a1 += W_out[(4*c4+1) * 16 + j] * hnew[j];
            a2 += W_out[(4*c4+2) * 16 + j] * hnew[j];
            a3 += W_out[(4*c4+3) * 16 + j] * hnew[j];
        }
        float4 o; o.x = a0; o.y = a1; o.z = a2; o.w = a3;
        op[c4] = o;
    }
}

extern "C" void kernel_launch(void* const* d_in, const int* in_sizes, int n_in,
                              void* d_out, int out_size, void* d_ws, size_t ws_size,
                              hipStream_t stream) {
    const float* feat     = (const float*)d_in[0];
    const int*   src      = (const int*)d_in[1];
    const int*   dst      = (const int*)d_in[2];
    const int*   etype    = (const int*)d_in[3];
    const float* edge_emb = (const float*)d_in[4];
    const float* W_ih     = (const float*)d_in[5];
    const float* W_hh     = (const float*)d_in[6];
    const float* b_ih     = (const float*)d_in[7];
    const float* b_hh     = (const float*)d_in[8];
    const float* W_out    = (const float*)d_in[9];
    const float* b_out    = (const float*)d_in[10];
    float* out  = (float*)d_out;
    float* magg = (float*)d_ws;   // [NNODES, MSG] accumulator

    hipMemsetAsync(magg, 0, (size_t)NNODES * MSG * sizeof(float), stream);
    ggnn_edge<<<2560, 256, 0, stream>>>(feat, src, dst, etype, edge_emb, magg);
    ggnn_node<<<(NNODES + 255) / 256, 256, 0, stream>>>(
        feat, magg, W_ih, W_hh, b_ih, b_hh, W_out, b_out, out);
}